// Round 1
// baseline (801.853 us; speedup 1.0000x reference)
//
#include <hip/hip_runtime.h>
#include <hip/hip_bf16.h>
#include <math.h>

#define Bb 32
#define N1c 331
#define N2c 256
#define Dc 256
#define Hc 8
#define DHc 32
#define Sc 587

__device__ __forceinline__ float eluf(float x) { return x > 0.f ? x : expm1f(x); }

__device__ __forceinline__ unsigned int packbf2(float x, float y) {
  unsigned int bx = __float_as_uint(x);
  unsigned int by = __float_as_uint(y);
  bx = (bx + 0x8000u) >> 16;
  by = (by + 0x8000u) & 0xffff0000u;
  return bx | by;
}

// ---------------- routing: w[b,4] ----------------
__device__ __forceinline__ float block_reduce_sum(float v, float* red) {
#pragma unroll
  for (int off = 32; off > 0; off >>= 1) v += __shfl_down(v, off, 64);
  const int lane = threadIdx.x & 63, wid = threadIdx.x >> 6;
  __syncthreads();
  if (lane == 0) red[wid] = v;
  __syncthreads();
  return red[0] + red[1] + red[2] + red[3];
}

__global__ __launch_bounds__(256) void routing_kernel(
    const float* __restrict__ x1, const float* __restrict__ x2,
    const float* __restrict__ r_w1, const float* __restrict__ r_b1,
    const float* __restrict__ r_g, const float* __restrict__ r_beta,
    const float* __restrict__ r_w2, const float* __restrict__ r_b2,
    float* __restrict__ wout) {
  const int b = blockIdx.x, t = threadIdx.x;
  __shared__ float m[512];
  __shared__ float red[4];

  float s = 0.f;
  const float* xp = x1 + (size_t)b * N1c * Dc + t;
  for (int n = 0; n < N1c; ++n) s += xp[(size_t)n * Dc];
  m[t] = s * (1.f / N1c);
  s = 0.f;
  const float* xp2 = x2 + (size_t)b * N2c * Dc + t;
  for (int n = 0; n < N2c; ++n) s += xp2[(size_t)n * Dc];
  m[256 + t] = s * (1.f / N2c);
  __syncthreads();

  float hv = r_b1[t];
  const float* wr = r_w1 + (size_t)t * 512;
#pragma unroll 4
  for (int k = 0; k < 512; k += 4) {
    float4 wv = *(const float4*)(wr + k);
    hv = fmaf(wv.x, m[k], hv);
    hv = fmaf(wv.y, m[k + 1], hv);
    hv = fmaf(wv.z, m[k + 2], hv);
    hv = fmaf(wv.w, m[k + 3], hv);
  }
  float mu = block_reduce_sum(hv, red) * (1.f / 256.f);
  float dv = hv - mu;
  float var = block_reduce_sum(dv * dv, red) * (1.f / 256.f);
  float hn = dv * rsqrtf(var + 1e-5f) * r_g[t] + r_beta[t];
  float ge = 0.5f * hn * (1.f + erff(hn * 0.70710678118654752f));

  float l0 = block_reduce_sum(ge * r_w2[0 * 256 + t], red) + r_b2[0];
  float l1 = block_reduce_sum(ge * r_w2[1 * 256 + t], red) + r_b2[1];
  float l2 = block_reduce_sum(ge * r_w2[2 * 256 + t], red) + r_b2[2];
  float l3 = block_reduce_sum(ge * r_w2[3 * 256 + t], red) + r_b2[3];
  if (t == 0) {
    float mx = fmaxf(fmaxf(l0, l1), fmaxf(l2, l3));
    float e0 = __expf(l0 - mx), e1 = __expf(l1 - mx), e2 = __expf(l2 - mx), e3 = __expf(l3 - mx);
    float inv = 1.f / (e0 + e1 + e2 + e3);
    wout[b * 4 + 0] = e0 * inv;
    wout[b * 4 + 1] = e1 * inv;
    wout[b * 4 + 2] = e2 * inv;
    wout[b * 4 + 3] = e3 * inv;
  }
}

// ---------------- generic C = act(A @ W^T + bias) ----------------
// AMODE 0: A is M x K row-major.  AMODE 1: virtual comb rows (x1|x2 concat along tokens).
template <int ACT, int AMODE>
__global__ __launch_bounds__(256) void gemm_xwT(
    const float* __restrict__ A, const float* __restrict__ x1,
    const float* __restrict__ x2, const float* __restrict__ W,
    const float* __restrict__ bias, float* __restrict__ C, int ldc, int M,
    int N, int K) {
  __shared__ float As[16][68];
  __shared__ float Bs[16][68];
  const int tid = threadIdx.x;
  const int m0 = blockIdx.y * 64;
  const int n0 = blockIdx.x * 64;
  const int tx = tid & 15, ty = tid >> 4;
  float acc[4][4] = {};

  const int sa_m = tid >> 2;
  const int sa_k = (tid & 3) * 4;

  int grow = m0 + sa_m;
  const bool rowok = grow < M;
  int crow = rowok ? grow : (M - 1);
  const float* arow;
  if (AMODE == 0) {
    arow = A + (size_t)crow * K;
  } else {
    int bidx = crow / Sc;
    int sidx = crow - bidx * Sc;
    arow = (sidx < N1c) ? (x1 + ((size_t)bidx * N1c + sidx) * Dc)
                        : (x2 + ((size_t)bidx * N2c + (sidx - N1c)) * Dc);
  }
  const float* wrow = W + (size_t)(n0 + sa_m) * K;

  for (int k0 = 0; k0 < K; k0 += 16) {
    float4 av = rowok ? *(const float4*)(arow + k0 + sa_k)
                      : make_float4(0.f, 0.f, 0.f, 0.f);
    float4 wv = *(const float4*)(wrow + k0 + sa_k);
    __syncthreads();
    As[sa_k + 0][sa_m] = av.x;
    As[sa_k + 1][sa_m] = av.y;
    As[sa_k + 2][sa_m] = av.z;
    As[sa_k + 3][sa_m] = av.w;
    Bs[sa_k + 0][sa_m] = wv.x;
    Bs[sa_k + 1][sa_m] = wv.y;
    Bs[sa_k + 2][sa_m] = wv.z;
    Bs[sa_k + 3][sa_m] = wv.w;
    __syncthreads();
#pragma unroll
    for (int kk = 0; kk < 16; ++kk) {
      float4 a = *(const float4*)&As[kk][ty * 4];
      float4 bv = *(const float4*)&Bs[kk][tx * 4];
      acc[0][0] = fmaf(a.x, bv.x, acc[0][0]);
      acc[0][1] = fmaf(a.x, bv.y, acc[0][1]);
      acc[0][2] = fmaf(a.x, bv.z, acc[0][2]);
      acc[0][3] = fmaf(a.x, bv.w, acc[0][3]);
      acc[1][0] = fmaf(a.y, bv.x, acc[1][0]);
      acc[1][1] = fmaf(a.y, bv.y, acc[1][1]);
      acc[1][2] = fmaf(a.y, bv.z, acc[1][2]);
      acc[1][3] = fmaf(a.y, bv.w, acc[1][3]);
      acc[2][0] = fmaf(a.z, bv.x, acc[2][0]);
      acc[2][1] = fmaf(a.z, bv.y, acc[2][1]);
      acc[2][2] = fmaf(a.z, bv.z, acc[2][2]);
      acc[2][3] = fmaf(a.z, bv.w, acc[2][3]);
      acc[3][0] = fmaf(a.w, bv.x, acc[3][0]);
      acc[3][1] = fmaf(a.w, bv.y, acc[3][1]);
      acc[3][2] = fmaf(a.w, bv.z, acc[3][2]);
      acc[3][3] = fmaf(a.w, bv.w, acc[3][3]);
    }
  }
  const int col = n0 + tx * 4;
  float4 bv4 = *(const float4*)(bias + col);
#pragma unroll
  for (int i = 0; i < 4; ++i) {
    int row = m0 + ty * 4 + i;
    if (row >= M) continue;
    float4 r;
    r.x = acc[i][0] + bv4.x;
    r.y = acc[i][1] + bv4.y;
    r.z = acc[i][2] + bv4.z;
    r.w = acc[i][3] + bv4.w;
    if (ACT == 1) {
      r.x = eluf(r.x);
      r.y = eluf(r.y);
      r.z = eluf(r.z);
      r.w = eluf(r.w);
    }
    *(float4*)(C + (size_t)row * ldc + col) = r;
  }
}

// ---------------- xout[b] += elu(add_w3 @ x2[b] + add_b3[p]) ----------------
__global__ __launch_bounds__(256) void gemm_w3x2(
    const float* __restrict__ w3, const float* __restrict__ x2,
    const float* __restrict__ b3, float* __restrict__ xout) {
  const int bz = blockIdx.z;
  const int p0 = blockIdx.y * 64;
  const int d0 = blockIdx.x * 64;
  __shared__ float As[16][68];
  __shared__ float Bs[16][68];
  const int tid = threadIdx.x;
  const int tx = tid & 15, ty = tid >> 4;
  float acc[4][4] = {};

  const int sa_m = tid >> 2;
  const int sa_k = (tid & 3) * 4;
  const int sb_k = tid >> 4;
  const int sb_d = (tid & 15) * 4;

  const float* x2b = x2 + (size_t)bz * N2c * Dc;
  int prow = p0 + sa_m;
  const bool rowok = prow < N1c;
  const float* arow = w3 + (size_t)(rowok ? prow : (N1c - 1)) * N2c;

  for (int k0 = 0; k0 < N2c; k0 += 16) {
    float4 av = rowok ? *(const float4*)(arow + k0 + sa_k)
                      : make_float4(0.f, 0.f, 0.f, 0.f);
    float4 bv = *(const float4*)(x2b + (size_t)(k0 + sb_k) * Dc + d0 + sb_d);
    __syncthreads();
    As[sa_k + 0][sa_m] = av.x;
    As[sa_k + 1][sa_m] = av.y;
    As[sa_k + 2][sa_m] = av.z;
    As[sa_k + 3][sa_m] = av.w;
    Bs[sb_k][sb_d + 0] = bv.x;
    Bs[sb_k][sb_d + 1] = bv.y;
    Bs[sb_k][sb_d + 2] = bv.z;
    Bs[sb_k][sb_d + 3] = bv.w;
    __syncthreads();
#pragma unroll
    for (int kk = 0; kk < 16; ++kk) {
      float4 a = *(const float4*)&As[kk][ty * 4];
      float4 bb = *(const float4*)&Bs[kk][tx * 4];
      acc[0][0] = fmaf(a.x, bb.x, acc[0][0]);
      acc[0][1] = fmaf(a.x, bb.y, acc[0][1]);
      acc[0][2] = fmaf(a.x, bb.z, acc[0][2]);
      acc[0][3] = fmaf(a.x, bb.w, acc[0][3]);
      acc[1][0] = fmaf(a.y, bb.x, acc[1][0]);
      acc[1][1] = fmaf(a.y, bb.y, acc[1][1]);
      acc[1][2] = fmaf(a.y, bb.z, acc[1][2]);
      acc[1][3] = fmaf(a.y, bb.w, acc[1][3]);
      acc[2][0] = fmaf(a.z, bb.x, acc[2][0]);
      acc[2][1] = fmaf(a.z, bb.y, acc[2][1]);
      acc[2][2] = fmaf(a.z, bb.z, acc[2][2]);
      acc[2][3] = fmaf(a.z, bb.w, acc[2][3]);
      acc[3][0] = fmaf(a.w, bb.x, acc[3][0]);
      acc[3][1] = fmaf(a.w, bb.y, acc[3][1]);
      acc[3][2] = fmaf(a.w, bb.z, acc[3][2]);
      acc[3][3] = fmaf(a.w, bb.w, acc[3][3]);
    }
  }
#pragma unroll
  for (int i = 0; i < 4; ++i) {
    int p = p0 + ty * 4 + i;
    if (p >= N1c) continue;
    float bbias = b3[p];
    float* cp = xout + ((size_t)bz * N1c + p) * Dc + d0 + tx * 4;
    float4 cur = *(float4*)cp;
    cur.x += eluf(acc[i][0] + bbias);
    cur.y += eluf(acc[i][1] + bbias);
    cur.z += eluf(acc[i][2] + bbias);
    cur.w += eluf(acc[i][3] + bbias);
    *(float4*)cp = cur;
  }
}

// ---------------- attention: o_pre = softmax(qk/sqrt(dh)) @ v ----------------
__global__ __launch_bounds__(256, 2) void attn_kernel(
    const float* __restrict__ qkv, float* __restrict__ o_pre) {
  const int bh = blockIdx.x;
  const int chunk = blockIdx.y;
  const int b = bh >> 3, h = bh & 7;
  const int tid = threadIdx.x;
  __shared__ unsigned int Kl[Sc * 16];
  __shared__ unsigned int Vl[Sc * 16];
  const size_t base = (size_t)b * Sc * 768;

  for (int p = tid; p < Sc * 16; p += 256) {
    int s = p >> 4, dp = (p & 15) * 2;
    const float* kr = qkv + base + (size_t)s * 768 + 256 + h * 32 + dp;
    float2 k2 = *(const float2*)kr;
    float2 v2 = *(const float2*)(kr + 256);
    Kl[p] = packbf2(k2.x, k2.y);
    Vl[p] = packbf2(v2.x, v2.y);
  }
  __syncthreads();

  const int qstart = chunk ? 296 : 0;
  const int qcnt = chunk ? 291 : 296;
  const int r0 = qstart + tid;
  const int r1 = qstart + 256 + tid;
  const bool has1 = (256 + tid) < qcnt;

  const float scale = 0.17677669529663688f;  // 1/sqrt(32)
  float q0[32], q1[32], acc0[32] = {}, acc1[32] = {};
  {
    const float* qp = qkv + base + (size_t)r0 * 768 + h * 32;
#pragma unroll
    for (int i = 0; i < 32; i += 4) {
      float4 v = *(const float4*)(qp + i);
      q0[i] = v.x * scale;
      q0[i + 1] = v.y * scale;
      q0[i + 2] = v.z * scale;
      q0[i + 3] = v.w * scale;
    }
    if (has1) {
      const float* qp1 = qkv + base + (size_t)r1 * 768 + h * 32;
#pragma unroll
      for (int i = 0; i < 32; i += 4) {
        float4 v = *(const float4*)(qp1 + i);
        q1[i] = v.x * scale;
        q1[i + 1] = v.y * scale;
        q1[i + 2] = v.z * scale;
        q1[i + 3] = v.w * scale;
      }
    } else {
#pragma unroll
      for (int i = 0; i < 32; ++i) q1[i] = 0.f;
    }
  }
  float m0r = -1e30f, l0 = 0.f, m1r = -1e30f, l1 = 0.f;

  for (int j = 0; j < Sc; ++j) {
    float kf[32];
    {
      const uint4* kp = reinterpret_cast<const uint4*>(Kl + (j << 4));
#pragma unroll
      for (int qq = 0; qq < 4; ++qq) {
        uint4 u = kp[qq];
        kf[qq * 8 + 0] = __uint_as_float(u.x << 16);
        kf[qq * 8 + 1] = __uint_as_float(u.x & 0xffff0000u);
        kf[qq * 8 + 2] = __uint_as_float(u.y << 16);
        kf[qq * 8 + 3] = __uint_as_float(u.y & 0xffff0000u);
        kf[qq * 8 + 4] = __uint_as_float(u.z << 16);
        kf[qq * 8 + 5] = __uint_as_float(u.z & 0xffff0000u);
        kf[qq * 8 + 6] = __uint_as_float(u.w << 16);
        kf[qq * 8 + 7] = __uint_as_float(u.w & 0xffff0000u);
      }
    }
    float s0 = 0.f, s1 = 0.f;
#pragma unroll
    for (int i = 0; i < 32; ++i) {
      s0 = fmaf(q0[i], kf[i], s0);
      s1 = fmaf(q1[i], kf[i], s1);
    }
    if (s0 > m0r) {
      float c = __expf(m0r - s0);
      l0 *= c;
#pragma unroll
      for (int i = 0; i < 32; ++i) acc0[i] *= c;
      m0r = s0;
    }
    float p0 = __expf(s0 - m0r);
    l0 += p0;
    if (s1 > m1r) {
      float c = __expf(m1r - s1);
      l1 *= c;
#pragma unroll
      for (int i = 0; i < 32; ++i) acc1[i] *= c;
      m1r = s1;
    }
    float p1 = __expf(s1 - m1r);
    l1 += p1;

    float vf[32];
    {
      const uint4* vp = reinterpret_cast<const uint4*>(Vl + (j << 4));
#pragma unroll
      for (int qq = 0; qq < 4; ++qq) {
        uint4 u = vp[qq];
        vf[qq * 8 + 0] = __uint_as_float(u.x << 16);
        vf[qq * 8 + 1] = __uint_as_float(u.x & 0xffff0000u);
        vf[qq * 8 + 2] = __uint_as_float(u.y << 16);
        vf[qq * 8 + 3] = __uint_as_float(u.y & 0xffff0000u);
        vf[qq * 8 + 4] = __uint_as_float(u.z << 16);
        vf[qq * 8 + 5] = __uint_as_float(u.z & 0xffff0000u);
        vf[qq * 8 + 6] = __uint_as_float(u.w << 16);
        vf[qq * 8 + 7] = __uint_as_float(u.w & 0xffff0000u);
      }
    }
#pragma unroll
    for (int i = 0; i < 32; ++i) {
      acc0[i] = fmaf(p0, vf[i], acc0[i]);
      acc1[i] = fmaf(p1, vf[i], acc1[i]);
    }
  }

  {
    float inv0 = 1.f / l0;
    float* op = o_pre + ((size_t)b * Sc + r0) * 256 + h * 32;
#pragma unroll
    for (int i = 0; i < 32; i += 4) {
      float4 v;
      v.x = acc0[i] * inv0;
      v.y = acc0[i + 1] * inv0;
      v.z = acc0[i + 2] * inv0;
      v.w = acc0[i + 3] * inv0;
      *(float4*)(op + i) = v;
    }
    if (has1) {
      float inv1 = 1.f / l1;
      float* op1 = o_pre + ((size_t)b * Sc + r1) * 256 + h * 32;
#pragma unroll
      for (int i = 0; i < 32; i += 4) {
        float4 v;
        v.x = acc1[i] * inv1;
        v.y = acc1[i + 1] * inv1;
        v.z = acc1[i + 2] * inv1;
        v.w = acc1[i + 3] * inv1;
        *(float4*)(op1 + i) = v;
      }
    }
  }
}

// ---------------- final combine ----------------
__global__ __launch_bounds__(256) void combine_kernel(
    const float* __restrict__ lo, const float* __restrict__ xout,
    const float* __restrict__ o, const float* __restrict__ x1,
    const float* __restrict__ x2, const float* __restrict__ wb,
    float* __restrict__ out) {
  const int gene4 = Bb * N1c * Dc / 4;
  const int img4 = Bb * N2c * Dc / 4;
  int idx = blockIdx.x * 256 + threadIdx.x;
  if (idx >= gene4 + img4) return;
  if (idx < gene4) {
    int e = idx * 4;
    int b = e / (N1c * Dc);
    int rem = e - b * (N1c * Dc);
    int n = rem >> 8, d = rem & 255;
    float w0 = wb[b * 4 + 0], w1 = wb[b * 4 + 1], w2 = wb[b * 4 + 2],
          w3 = wb[b * 4 + 3];
    float4 g0 = *(const float4*)(lo + ((size_t)b * Sc + n) * Dc + d);
    float4 g1 = *(const float4*)(xout + ((size_t)b * N1c + n) * Dc + d);
    float4 g2 = *(const float4*)(o + ((size_t)b * Sc + n) * Dc + d);
    float4 g3 = *(const float4*)(x1 + e);
    float4 r;
    r.x = w0 * g0.x + w1 * g1.x + w2 * g2.x + w3 * g3.x;
    r.y = w0 * g0.y + w1 * g1.y + w2 * g2.y + w3 * g3.y;
    r.z = w0 * g0.z + w1 * g1.z + w2 * g2.z + w3 * g3.z;
    r.w = w0 * g0.w + w1 * g1.w + w2 * g2.w + w3 * g3.w;
    *(float4*)(out + e) = r;
  } else {
    int e = (idx - gene4) * 4;
    int b = e >> 16;
    int rem = e & 65535;
    int n = rem >> 8, d = rem & 255;
    float w0 = wb[b * 4 + 0], w1 = wb[b * 4 + 1], w2 = wb[b * 4 + 2],
          w3 = wb[b * 4 + 3];
    float4 g0 = *(const float4*)(lo + ((size_t)b * Sc + N1c + n) * Dc + d);
    float4 g1 = *(const float4*)(xout + ((size_t)b * N1c + n) * Dc + d);
    float4 g2 = *(const float4*)(o + ((size_t)b * Sc + N1c + n) * Dc + d);
    float4 g3 = *(const float4*)(x2 + e);
    float4 r;
    r.x = w0 * g0.x + w1 * g1.x + w2 * g2.x + w3 * g3.x;
    r.y = w0 * g0.y + w1 * g1.y + w2 * g2.y + w3 * g3.y;
    r.z = w0 * g0.z + w1 * g1.z + w2 * g2.z + w3 * g3.z;
    r.w = w0 * g0.w + w1 * g1.w + w2 * g2.w + w3 * g3.w;
    *(float4*)(out + (size_t)(Bb * N1c * Dc) + e) = r;
  }
}

extern "C" void kernel_launch(void* const* d_in, const int* in_sizes, int n_in,
                              void* d_out, int out_size, void* d_ws,
                              size_t ws_size, hipStream_t stream) {
  const float* x1 = (const float*)d_in[0];
  const float* x2 = (const float*)d_in[1];
  const float* r_w1 = (const float*)d_in[2];
  const float* r_b1 = (const float*)d_in[3];
  const float* r_g = (const float*)d_in[4];
  const float* r_beta = (const float*)d_in[5];
  const float* r_w2 = (const float*)d_in[6];
  const float* r_b2 = (const float*)d_in[7];
  const float* lin_w = (const float*)d_in[8];
  const float* lin_b = (const float*)d_in[9];
  const float* add_w2 = (const float*)d_in[10];
  const float* add_b2 = (const float*)d_in[11];
  const float* add_w3 = (const float*)d_in[12];
  const float* add_b3 = (const float*)d_in[13];
  const float* attn_win = (const float*)d_in[14];
  const float* attn_bin = (const float*)d_in[15];
  const float* attn_wout = (const float*)d_in[16];
  const float* attn_bout = (const float*)d_in[17];
  float* out = (float*)d_out;
  float* ws = (float*)d_ws;

  // workspace layout (floats)
  float* lo = ws;                    // B*S*D      = 4,808,704
  float* xout = ws + 4808704;        // B*N1*D     = 2,711,552
  float* qkvb = ws + 7520256;        // B*S*768    = 14,426,112
  float* o_pre = ws + 21946368;      // B*S*D      = 4,808,704
  float* wroute = ws + 26755072;     // B*4
  float* ob = qkvb;                  // o aliases dead qkv buffer

  const int MS = Bb * Sc;    // 18784
  const int M1 = Bb * N1c;   // 10592

  routing_kernel<<<Bb, 256, 0, stream>>>(x1, x2, r_w1, r_b1, r_g, r_beta, r_w2,
                                         r_b2, wroute);
  // lo = elu(comb @ lin_w.T + lin_b)
  gemm_xwT<1, 1><<<dim3(4, (MS + 63) / 64), 256, 0, stream>>>(
      nullptr, x1, x2, lin_w, lin_b, lo, Dc, MS, Dc, Dc);
  // xout = elu(x1 @ add_w2.T + add_b2)
  gemm_xwT<1, 0><<<dim3(4, (M1 + 63) / 64), 256, 0, stream>>>(
      x1, nullptr, nullptr, add_w2, add_b2, xout, Dc, M1, Dc, Dc);
  // xout += elu(add_w3 @ x2[b] + add_b3)
  gemm_w3x2<<<dim3(4, 6, Bb), 256, 0, stream>>>(add_w3, x2, add_b3, xout);
  // qkv = comb @ attn_win.T + attn_bin
  gemm_xwT<0, 1><<<dim3(12, (MS + 63) / 64), 256, 0, stream>>>(
      nullptr, x1, x2, attn_win, attn_bin, qkvb, 768, MS, 768, Dc);
  // attention
  attn_kernel<<<dim3(Bb * Hc, 2), 256, 0, stream>>>(qkvb, o_pre);
  // o = o_pre @ attn_wout.T + attn_bout   (writes over dead qkv buffer)
  gemm_xwT<0, 0><<<dim3(4, (MS + 63) / 64), 256, 0, stream>>>(
      o_pre, nullptr, nullptr, attn_wout, attn_bout, ob, Dc, MS, Dc, Dc);
  // final weighted combine
  combine_kernel<<<4696, 256, 0, stream>>>(lo, xout, ob, x1, x2, wroute, out);
}